// Round 9
// baseline (394.415 us; speedup 1.0000x reference)
//
#include <hip/hip_runtime.h>
#include <hip/hip_bf16.h>

// CentralSpecificModel: per-species 2-layer MLP (256 -> 1024 -> 256), 4 species,
// N=65536 rows, fp32 in/out. Bucket rows by species; fused per-64-row-tile
// kernel does GEMM1+silu+GEMM2 with bf16 MFMA (16x16x32), swapped operands
// (weights as A, X/H as B -> H^T/Y^T), batched B-frag prefetch, dbuf Hs.
// R11: R10 (wave-skew flag protocol) got a container failure — can't tell
// infra flake from a HW hang. Resubmit the overlap theory with HALF the novel
// machinery: keep rdy publish flags (wave w releases Hs slice [32w,32w+32)
// after silu; GEMM2 acquire-polls slices own-first), DROP the dn buffer-reuse
// flags — replaced by one __syncthreads every TWO chunks (barrier at start of
// even chunk c guarantees GEMM2(c-2), the previous reader of Hs[c&1], is done
// in all waves). Skew bounded to <=2 chunks structurally; 4 barriers not 8;
// s_sleep(1) in spin bodies. Launcher = R8-verified 3-kernel form.
// Rationale: per-CU pipe sums (MFMA 33 + LDS 22 + VALU 24 + L2 29 ~= 108us)
// ~= measured 120us -> pipes don't overlap; de-phased waves let one wave's
// MFMA cover another's silu/L2 latency.

#define N_ATOMS 65536
#define D_IN 256
#define D_HID 1024
#define D_OUT 256
#define TPS 1024   // max 64-row tiles per species (worst case: all rows one species)

typedef __attribute__((ext_vector_type(8))) short short8;
typedef __attribute__((ext_vector_type(4))) float float4e;
typedef __attribute__((ext_vector_type(2))) unsigned uint2e;
typedef __attribute__((ext_vector_type(4))) unsigned uint4e;

// ws layout (bytes):
//   [0, 256)           cnt[4] padded: cnt[s] at int offset s*16 (64B apart)
//   [256, 1048832)     bucket[4][65536] int
//   [1048832, 3145984) W1 swizzled bf16 fragments (4*256*1024)
//   [3145984, 5243136) W2 swizzled bf16 fragments (4*1024*256)
#define WS_BUCKET_OFF 256
#define WS_W1_OFF 1048832
#define WS_W2_OFF 3145984

__device__ __forceinline__ short f2bf(float f) {
  unsigned u = __builtin_bit_cast(unsigned, f);
  unsigned r = (u + 0x7FFFu + ((u >> 16) & 1u)) >> 16;   // round-to-nearest-even
  return (short)r;
}

// Two f32 -> packed 2x bf16 in one instruction (low half = a, high half = b).
__device__ __forceinline__ unsigned cvt_pk_bf16(float a, float b) {
  unsigned r;
  asm("v_cvt_pk_bf16_f32 %0, %1, %2" : "=v"(r) : "v"(a), "v"(b));
  return r;
}

// Swizzle W1/W2 fp32 -> bf16 MFMA B-fragment order; zero padded counters.
// B-frag (16x16x32): lane l holds B[k0 + 8*(l>>4) + j][nt*16 + (l&15)], j=0..7.
// (Used as the A operand in the swapped fused kernel.)
__global__ void prep_kernel(const float* __restrict__ W1, const float* __restrict__ W2,
                            short* __restrict__ w1sw, short* __restrict__ w2sw,
                            int* __restrict__ cnt) {
  int gid = blockIdx.x * 256 + threadIdx.x;   // 262144 threads
  if (gid < 64) cnt[gid] = 0;
  int lane = gid & 63;
  int lr = lane & 15;
  int lk = (lane >> 4) * 8;
  if (gid < 131072) {            // W1: [4][256][1024], NT=64, KS=8
    int ks = (gid >> 6) & 7;
    int nt = (gid >> 9) & 63;
    int s  = gid >> 15;
    const float* src = W1 + ((size_t)(s * 256 + ks * 32 + lk)) * 1024 + nt * 16 + lr;
    short8 v;
    for (int j = 0; j < 8; ++j) v[j] = f2bf(src[(size_t)j * 1024]);
    *(short8*)(w1sw + (size_t)gid * 8) = v;
  } else {                       // W2: [4][1024][256], NT=16, KS=32
    int g = gid - 131072;
    int kt = (g >> 6) & 31;
    int nt = (g >> 11) & 15;
    int s  = g >> 15;
    const float* src = W2 + ((size_t)(s * 1024 + kt * 32 + lk)) * 256 + nt * 16 + lr;
    short8 v;
    for (int j = 0; j < 8; ++j) v[j] = f2bf(src[(size_t)j * 256]);
    *(short8*)(w2sw + (size_t)g * 8) = v;
  }
}

// Bucket rows by species. 32 blocks x 2048 rows. Two-pass block-internal
// histogram; ONE atomicAdd per species per block; then scatter.
#define CF_BLOCKS 32
#define CF_ITERS 8
__global__ void count_fill_kernel(const int* __restrict__ species,
                                  int* __restrict__ cnt, int* __restrict__ bucket) {
  int tid = threadIdx.x;
  int lane = tid & 63, wid = tid >> 6;
  __shared__ int wcnt[CF_ITERS][4][4];   // [iter][wave][species]
  __shared__ int wb[CF_ITERS][4][4];     // exclusive prefix within block
  __shared__ int base_sm[4];
  int sv[CF_ITERS], rk[CF_ITERS];
  unsigned long long below = (1ull << lane) - 1ull;
  int base_i = blockIdx.x * (CF_ITERS * 256);
  #pragma unroll
  for (int it = 0; it < CF_ITERS; ++it) {
    int s = species[base_i + it * 256 + tid] & 3;
    sv[it] = s;
    unsigned long long m0 = __ballot(s == 0);
    unsigned long long m1 = __ballot(s == 1);
    unsigned long long m2 = __ballot(s == 2);
    unsigned long long m3 = __ballot(s == 3);
    unsigned long long ms = (s == 0) ? m0 : (s == 1) ? m1 : (s == 2) ? m2 : m3;
    rk[it] = __popcll(ms & below);
    if (lane == 0) {
      wcnt[it][wid][0] = __popcll(m0);
      wcnt[it][wid][1] = __popcll(m1);
      wcnt[it][wid][2] = __popcll(m2);
      wcnt[it][wid][3] = __popcll(m3);
    }
  }
  __syncthreads();
  if (tid < 4) {
    int ss = tid, run = 0;
    for (int it = 0; it < CF_ITERS; ++it)
      for (int w = 0; w < 4; ++w) {
        wb[it][w][ss] = run;
        run += wcnt[it][w][ss];
      }
    base_sm[ss] = atomicAdd(&cnt[ss * 16], run);
  }
  __syncthreads();
  #pragma unroll
  for (int it = 0; it < CF_ITERS; ++it) {
    int ss = sv[it];
    bucket[ss * N_ATOMS + base_sm[ss] + wb[it][wid][ss] + rk[it]] = base_i + it * 256 + tid;
  }
}

// Fused per-tile MLP, swapped-operand form. Block = 256 threads (4 waves),
// tile = 64 rows. GEMM1: H^T = W1^T @ X^T, lane holds 4 consecutive hid ->
// packed 8B Hs writes. GEMM2: Y^T = W2^T @ H^T -> float4 epilogue stores.
// LDS: Xs 64x280 + Hs[2] 64x152 + rdy flags -> ~74784B, 2 blocks/CU.
// Wave-skew: rdy publish flags + barrier every 2 chunks (see header).
#define XS_STRIDE 280
#define HS_STRIDE 152
__global__ __launch_bounds__(256, 2) void fused_kernel(
    const float* __restrict__ x, const int* __restrict__ cntArr,
    const int* __restrict__ bucket, const short* __restrict__ w1sw,
    const short* __restrict__ w2sw, const float* __restrict__ b1,
    const float* __restrict__ b2, float* __restrict__ out) {
  int bid = blockIdx.x;
  // XCD swizzle: bid%8 round-robins XCDs; give species s to XCD pair {2s,2s+1}
  // so each XCD L2 only holds ~1MB of weight fragments.
  int s = (bid & 7) >> 1;
  int t = ((bid >> 3) << 1) | (bid & 1);
  int cnt = cntArr[s * 16];
  int r0 = t * 64;
  if (r0 >= cnt) return;
  int nrows = min(64, cnt - r0);
  const int* buck = bucket + s * N_ATOMS + r0;

  __shared__ short Xs[64 * XS_STRIDE];
  __shared__ short Hs[2][64 * HS_STRIDE];
  __shared__ int rdy[2][4];   // rdy[buf][w] = last chunk whose slice w is written

  int tid = threadIdx.x;
  if (tid < 8) rdy[tid >> 2][tid & 3] = -1;

  // Stage gathered x tile -> bf16 LDS (cvt_pk packed). 2048 8-elem groups.
  for (int i = 0; i < 8; ++i) {
    int id = tid + i * 256;
    int r = id >> 5;          // row 0..63
    int g = id & 31;          // 8-float group
    float4 f0 = {}, f1 = {};
    if (r < nrows) {
      const float4* src = (const float4*)(x + (size_t)buck[r] * D_IN + g * 8);
      f0 = src[0];
      f1 = src[1];
    }
    uint4e v;
    v.x = cvt_pk_bf16(f0.x, f0.y);
    v.y = cvt_pk_bf16(f0.z, f0.w);
    v.z = cvt_pk_bf16(f1.x, f1.y);
    v.w = cvt_pk_bf16(f1.z, f1.w);
    *(uint4e*)(Xs + r * XS_STRIDE + g * 8) = v;
  }

  int lane = tid & 63;
  int wid = tid >> 6;
  int lr = lane & 15;          // row within 16-tile (X-row in swapped form)
  int lk = (lane >> 4) * 8;    // k base within 32-kstep
  int lq = (lane >> 4) * 4;    // hid/out base within 16-tile

  // Row gather indices for the epilogue (per bt tile).
  int rowIdx[4];
  #pragma unroll
  for (int bt = 0; bt < 4; ++bt) {
    int r = bt * 16 + lr;
    rowIdx[bt] = (r < nrows) ? buck[r] : -1;
  }

  // accY init = b2 bias (folded). Wave covers out cols [wid*64, wid*64+64).
  float4e accY[4][4];
  #pragma unroll
  for (int at = 0; at < 4; ++at) {
    float4e bv = *(const float4e*)(b2 + s * D_OUT + wid * 64 + at * 16 + lq);
    #pragma unroll
    for (int bt = 0; bt < 4; ++bt) accY[at][bt] = bv;
  }

  // Preload GEMM1 W1-fragments for c=0 (16 batched loads, one latency exposure).
  short8 b1f[16];
  #pragma unroll
  for (int ks = 0; ks < 8; ++ks)
    #pragma unroll
    for (int at = 0; at < 2; ++at) {
      int nt = 0 * 8 + wid * 2 + at;
      b1f[ks * 2 + at] = *(const short8*)(w1sw + ((size_t)((s * 64 + nt) * 8 + ks)) * 512 + lane * 8);
    }

  __syncthreads();   // Xs ready + flags init

  for (int c = 0; c < 8; ++c) {
    int bsel = c & 1;
    // Hard sync at the start of even chunks (c>=2): guarantees GEMM2(c-2)
    // — the previous reader of Hs[bsel] — is complete in all waves, and
    // bounds wave skew to 2 chunks.
    if (c >= 2 && bsel == 0) __syncthreads();
    // acc1 init = b1 bias for this chunk's hid slice.
    float4e acc1[2][4];
    #pragma unroll
    for (int at = 0; at < 2; ++at) {
      float4e bv = *(const float4e*)(b1 + s * D_HID + c * 128 + wid * 32 + at * 16 + lq);
      #pragma unroll
      for (int bt = 0; bt < 4; ++bt) acc1[at][bt] = bv;
    }
    // ---- GEMM1: H^T chunk [128 hid x 64 rows] = W1^T @ X^T ----
    __builtin_amdgcn_s_setprio(1);
    #pragma unroll
    for (int ks = 0; ks < 8; ++ks) {
      short8 xb[4];
      #pragma unroll
      for (int bt = 0; bt < 4; ++bt)
        xb[bt] = *(const short8*)(Xs + (bt * 16 + lr) * XS_STRIDE + ks * 32 + lk);
      #pragma unroll
      for (int at = 0; at < 2; ++at)
        #pragma unroll
        for (int bt = 0; bt < 4; ++bt)
          acc1[at][bt] = __builtin_amdgcn_mfma_f32_16x16x32_bf16(b1f[ks * 2 + at], xb[bt], acc1[at][bt], 0, 0, 0);
    }
    __builtin_amdgcn_s_setprio(0);
    // ---- prefetch GEMM2 W2-fragments (latency hidden under silu) ----
    short8 b2f[16];
    #pragma unroll
    for (int ks = 0; ks < 4; ++ks)
      #pragma unroll
      for (int at = 0; at < 4; ++at) {
        int nt = wid * 4 + at;
        int kt = c * 4 + ks;
        b2f[ks * 4 + at] = *(const short8*)(w2sw + ((size_t)((s * 16 + nt) * 32 + kt)) * 512 + lane * 8);
      }
    // ---- silu -> Hs[bsel] slice wid (direct write, cvt_pk packed) ----
    short* hsb = Hs[bsel];
    #pragma unroll
    for (int at = 0; at < 2; ++at) {
      int hidloc = wid * 32 + at * 16 + lq;
      #pragma unroll
      for (int bt = 0; bt < 4; ++bt) {
        float4e v4 = acc1[at][bt];
        float sv0 = v4[0] * __builtin_amdgcn_rcpf(1.0f + __expf(-v4[0]));
        float sv1 = v4[1] * __builtin_amdgcn_rcpf(1.0f + __expf(-v4[1]));
        float sv2 = v4[2] * __builtin_amdgcn_rcpf(1.0f + __expf(-v4[2]));
        float sv3 = v4[3] * __builtin_amdgcn_rcpf(1.0f + __expf(-v4[3]));
        uint2e h;
        h.x = cvt_pk_bf16(sv0, sv1);
        h.y = cvt_pk_bf16(sv2, sv3);
        *(uint2e*)(hsb + (bt * 16 + lr) * HS_STRIDE + hidloc) = h;
      }
    }
    // Publish this wave's slice (release orders the Hs writes above).
    if (lane == 0)
      __hip_atomic_store(&rdy[bsel][wid], c, __ATOMIC_RELEASE, __HIP_MEMORY_SCOPE_WORKGROUP);
    // ---- prefetch next chunk's W1-fragments (hidden under GEMM2 MFMA) ----
    if (c < 7) {
      #pragma unroll
      for (int ks = 0; ks < 8; ++ks)
        #pragma unroll
        for (int at = 0; at < 2; ++at) {
          int nt = (c + 1) * 8 + wid * 2 + at;
          b1f[ks * 2 + at] = *(const short8*)(w1sw + ((size_t)((s * 64 + nt) * 8 + ks)) * 512 + lane * 8);
        }
    }
    // ---- GEMM2: consume slices own-first, acquire-poll the rest ----
    #pragma unroll
    for (int i = 0; i < 4; ++i) {
      int ks = (wid + i) & 3;
      if (i > 0) {
        while (__hip_atomic_load(&rdy[bsel][ks], __ATOMIC_ACQUIRE, __HIP_MEMORY_SCOPE_WORKGROUP) < c)
          __builtin_amdgcn_s_sleep(1);
      }
      short8 hb[4];
      #pragma unroll
      for (int bt = 0; bt < 4; ++bt)
        hb[bt] = *(const short8*)(hsb + (bt * 16 + lr) * HS_STRIDE + ks * 32 + lk);
      __builtin_amdgcn_s_setprio(1);
      #pragma unroll
      for (int at = 0; at < 4; ++at)
        #pragma unroll
        for (int bt = 0; bt < 4; ++bt)
          accY[at][bt] = __builtin_amdgcn_mfma_f32_16x16x32_bf16(b2f[ks * 4 + at], hb[bt], accY[at][bt], 0, 0, 0);
      __builtin_amdgcn_s_setprio(0);
    }
  }

  // ---- epilogue: scatter Y rows, 16B per lane (bias already folded in) ----
  #pragma unroll
  for (int at = 0; at < 4; ++at) {
    int nb = wid * 64 + at * 16 + lq;
    #pragma unroll
    for (int bt = 0; bt < 4; ++bt) {
      if (rowIdx[bt] >= 0)
        *(float4e*)(out + (size_t)rowIdx[bt] * D_OUT + nb) = accY[at][bt];
    }
  }
}

extern "C" void kernel_launch(void* const* d_in, const int* in_sizes, int n_in,
                              void* d_out, int out_size, void* d_ws, size_t ws_size,
                              hipStream_t stream) {
  const float* x  = (const float*)d_in[0];
  const int* spc  = (const int*)d_in[1];
  const float* W1 = (const float*)d_in[2];
  const float* b1 = (const float*)d_in[3];
  const float* W2 = (const float*)d_in[4];
  const float* b2 = (const float*)d_in[5];
  float* out = (float*)d_out;

  int*   cnt    = (int*)d_ws;
  int*   bucket = (int*)((char*)d_ws + WS_BUCKET_OFF);
  short* w1sw   = (short*)((char*)d_ws + WS_W1_OFF);
  short* w2sw   = (short*)((char*)d_ws + WS_W2_OFF);

  prep_kernel<<<1024, 256, 0, stream>>>(W1, W2, w1sw, w2sw, cnt);
  count_fill_kernel<<<CF_BLOCKS, 256, 0, stream>>>(spc, cnt, bucket);
  fused_kernel<<<4 * TPS, 256, 0, stream>>>(x, cnt, bucket, w1sw, w2sw, b1, b2, out);
}

// Round 10
// 232.712 us; speedup vs baseline: 1.6949x; 1.6949x over previous
//
#include <hip/hip_runtime.h>
#include <hip/hip_bf16.h>

// CentralSpecificModel: per-species 2-layer MLP (256 -> 1024 -> 256), 4 species,
// N=65536 rows, fp32 in/out. Bucket rows by species; fused per-64-row-tile
// kernel does GEMM1+silu+GEMM2, swapped operands (weights as A, X/H as B ->
// H^T/Y^T), batched frag prefetch, dbuf Hs, ONE barrier per chunk (R3/R8-proven).
// R12: R10/R11 intra-block skew protocols abandoned (R11: acquire-polls inside
// unrolled GEMM2 split accY live ranges -> 0.65GB scratch spill, 297us).
// Back to R8 skeleton; switch MFMA shape 16x16x32 -> 32x32x16: same FLOPs &
// operand bytes, but matrix pipe runs 2495 vs 2075 TF (m119/m06) and MFMA
// instr count halves (128->64 per wave-chunk). C/D layout = m74-verified
// col=lane&31, row=(reg&3)+8*(reg>>2)+4*(lane>>5); A/B layouts extend the
// working 16x16 pattern (K halves in lane>>5). Hs writes stay 8B-packed,
// epilogue stays float4. Register budget identical to R8 (no spill expected).
// Also: count_fill 32->8 blocks (global atomic chain depth 32->8).

#define N_ATOMS 65536
#define D_IN 256
#define D_HID 1024
#define D_OUT 256
#define TPS 1024   // max 64-row tiles per species (worst case: all rows one species)

typedef __attribute__((ext_vector_type(8))) short short8;
typedef __attribute__((ext_vector_type(4))) float float4e;
typedef __attribute__((ext_vector_type(16))) float f32x16;
typedef __attribute__((ext_vector_type(2))) unsigned uint2e;
typedef __attribute__((ext_vector_type(4))) unsigned uint4e;

// ws layout (bytes):
//   [0, 256)           cnt[4] padded: cnt[s] at int offset s*16 (64B apart)
//   [256, 1048832)     bucket[4][65536] int
//   [1048832, 3145984) W1 swizzled bf16 fragments (4*256*1024)
//   [3145984, 5243136) W2 swizzled bf16 fragments (4*1024*256)
#define WS_BUCKET_OFF 256
#define WS_W1_OFF 1048832
#define WS_W2_OFF 3145984

__device__ __forceinline__ short f2bf(float f) {
  unsigned u = __builtin_bit_cast(unsigned, f);
  unsigned r = (u + 0x7FFFu + ((u >> 16) & 1u)) >> 16;   // round-to-nearest-even
  return (short)r;
}

// Two f32 -> packed 2x bf16 in one instruction (low half = a, high half = b).
__device__ __forceinline__ unsigned cvt_pk_bf16(float a, float b) {
  unsigned r;
  asm("v_cvt_pk_bf16_f32 %0, %1, %2" : "=v"(r) : "v"(a), "v"(b));
  return r;
}

// Swizzle W1/W2 fp32 -> bf16 MFMA 32x32x16 A-fragment order (swapped form:
// weights are the A operand, A = W^T). Lane l of frag (nt,kt) holds
// W[kt*16 + 8*(l>>5) + j][nt*32 + (l&31)], j=0..7 (16B contiguous per lane).
// W1: 4 species x 32 nt x 16 kt frags; W2: 4 x 8 nt x 64 kt frags.
__global__ void prep_kernel(const float* __restrict__ W1, const float* __restrict__ W2,
                            short* __restrict__ w1sw, short* __restrict__ w2sw,
                            int* __restrict__ cnt) {
  int gid = blockIdx.x * 256 + threadIdx.x;   // 262144 threads
  if (gid < 64) cnt[gid] = 0;
  int lane = gid & 63;
  int lc = lane & 31;            // output-dim col within 32-tile
  int lk = (lane >> 5) * 8;      // k base within 16-kstep
  if (gid < 131072) {            // W1: [4][256][1024], NT=32, KT=16
    int kt = (gid >> 6) & 15;
    int nt = (gid >> 10) & 31;
    int s  = gid >> 15;
    const float* src = W1 + ((size_t)(s * 256 + kt * 16 + lk)) * 1024 + nt * 32 + lc;
    short8 v;
    for (int j = 0; j < 8; ++j) v[j] = f2bf(src[(size_t)j * 1024]);
    *(short8*)(w1sw + (size_t)gid * 8) = v;
  } else {                       // W2: [4][1024][256], NT=8, KT=64
    int g = gid - 131072;
    int kt = (g >> 6) & 63;
    int nt = (g >> 12) & 7;
    int s  = g >> 15;
    const float* src = W2 + ((size_t)(s * 1024 + kt * 16 + lk)) * 256 + nt * 32 + lc;
    short8 v;
    for (int j = 0; j < 8; ++j) v[j] = f2bf(src[(size_t)j * 256]);
    *(short8*)(w2sw + (size_t)g * 8) = v;
  }
}

// Bucket rows by species. 8 blocks x 8192 rows (atomic chain depth 8).
// Two-pass block-internal histogram; ONE atomicAdd per species per block.
#define CF_BLOCKS 8
#define CF_ITERS 32
__global__ void count_fill_kernel(const int* __restrict__ species,
                                  int* __restrict__ cnt, int* __restrict__ bucket) {
  int tid = threadIdx.x;
  int lane = tid & 63, wid = tid >> 6;
  __shared__ int wcnt[CF_ITERS][4][4];   // [iter][wave][species]
  __shared__ int wb[CF_ITERS][4][4];     // exclusive prefix within block
  __shared__ int base_sm[4];
  int sv[CF_ITERS], rk[CF_ITERS];
  unsigned long long below = (1ull << lane) - 1ull;
  int base_i = blockIdx.x * (CF_ITERS * 256);
  #pragma unroll
  for (int it = 0; it < CF_ITERS; ++it) {
    int s = species[base_i + it * 256 + tid] & 3;
    sv[it] = s;
    unsigned long long m0 = __ballot(s == 0);
    unsigned long long m1 = __ballot(s == 1);
    unsigned long long m2 = __ballot(s == 2);
    unsigned long long m3 = __ballot(s == 3);
    unsigned long long ms = (s == 0) ? m0 : (s == 1) ? m1 : (s == 2) ? m2 : m3;
    rk[it] = __popcll(ms & below);
    if (lane == 0) {
      wcnt[it][wid][0] = __popcll(m0);
      wcnt[it][wid][1] = __popcll(m1);
      wcnt[it][wid][2] = __popcll(m2);
      wcnt[it][wid][3] = __popcll(m3);
    }
  }
  __syncthreads();
  if (tid < 4) {
    int ss = tid, run = 0;
    for (int it = 0; it < CF_ITERS; ++it)
      for (int w = 0; w < 4; ++w) {
        wb[it][w][ss] = run;
        run += wcnt[it][w][ss];
      }
    base_sm[ss] = atomicAdd(&cnt[ss * 16], run);
  }
  __syncthreads();
  #pragma unroll
  for (int it = 0; it < CF_ITERS; ++it) {
    int ss = sv[it];
    bucket[ss * N_ATOMS + base_sm[ss] + wb[it][wid][ss] + rk[it]] = base_i + it * 256 + tid;
  }
}

// Fused per-tile MLP, swapped-operand 32x32x16 form. Block = 256 threads
// (4 waves), tile = 64 rows (2 row-tiles of 32). Per chunk c (8 x 128 hid):
// GEMM1: wave owns hid-tile nt=c*4+wid (32 hid x 64 rows), 16 ksteps x 2 bt;
// silu -> Hs[c&1]; barrier; GEMM2: wave owns out cols [wid*64,+64) (2 out-
// tiles), 8 ksteps x 2 ot x 2 bt. C/D: col(=x-row)=lane&31,
// row(=hid/out)=(reg&3)+8*(reg>>2)+4*(lane>>5) -> 4-consecutive groups.
// LDS: Xs 64x280 + Hs[2] 64x152 = 74752B -> 2 blocks/CU.
#define XS_STRIDE 280
#define HS_STRIDE 152
__global__ __launch_bounds__(256, 2) void fused_kernel(
    const float* __restrict__ x, const int* __restrict__ cntArr,
    const int* __restrict__ bucket, const short* __restrict__ w1sw,
    const short* __restrict__ w2sw, const float* __restrict__ b1,
    const float* __restrict__ b2, float* __restrict__ out) {
  int bid = blockIdx.x;
  // XCD swizzle: bid%8 round-robins XCDs; give species s to XCD pair {2s,2s+1}
  // so each XCD L2 only holds ~1MB of weight fragments.
  int s = (bid & 7) >> 1;
  int t = ((bid >> 3) << 1) | (bid & 1);
  int cnt = cntArr[s * 16];
  int r0 = t * 64;
  if (r0 >= cnt) return;
  int nrows = min(64, cnt - r0);
  const int* buck = bucket + s * N_ATOMS + r0;

  __shared__ short Xs[64 * XS_STRIDE];
  __shared__ short Hs[2][64 * HS_STRIDE];

  int tid = threadIdx.x;

  // Stage gathered x tile -> bf16 LDS (cvt_pk packed). 2048 8-elem groups.
  for (int i = 0; i < 8; ++i) {
    int id = tid + i * 256;
    int r = id >> 5;          // row 0..63
    int g = id & 31;          // 8-float group
    float4 f0 = {}, f1 = {};
    if (r < nrows) {
      const float4* src = (const float4*)(x + (size_t)buck[r] * D_IN + g * 8);
      f0 = src[0];
      f1 = src[1];
    }
    uint4e v;
    v.x = cvt_pk_bf16(f0.x, f0.y);
    v.y = cvt_pk_bf16(f0.z, f0.w);
    v.z = cvt_pk_bf16(f1.x, f1.y);
    v.w = cvt_pk_bf16(f1.z, f1.w);
    *(uint4e*)(Xs + r * XS_STRIDE + g * 8) = v;
  }

  int lane = tid & 63;
  int wid = tid >> 6;
  int lr = lane & 31;          // x-row within 32-tile (C/D col)
  int hk = lane >> 5;          // K-half select (0/1); also C/D row +4 offset
  int lk = hk * 8;             // k base within 16-kstep

  // Row gather indices for the epilogue (per 32-row tile).
  int rowIdx[2];
  #pragma unroll
  for (int bt = 0; bt < 2; ++bt) {
    int r = bt * 32 + lr;
    rowIdx[bt] = (r < nrows) ? buck[r] : -1;
  }

  // accY init = b2 bias (folded). Wave covers out cols [wid*64, wid*64+64).
  // acc element 4g+q <-> out offset g*8 + hk*4 + q.
  f32x16 accY[2][2];
  #pragma unroll
  for (int ot = 0; ot < 2; ++ot) {
    #pragma unroll
    for (int g = 0; g < 4; ++g) {
      float4e bv = *(const float4e*)(b2 + s * D_OUT + wid * 64 + ot * 32 + g * 8 + hk * 4);
      #pragma unroll
      for (int q = 0; q < 4; ++q) {
        accY[ot][0][g * 4 + q] = bv[q];
        accY[ot][1][g * 4 + q] = bv[q];
      }
    }
  }

  // Preload GEMM1 W1-fragments for c=0 (16 batched loads, one latency exposure).
  short8 b1f[16];
  #pragma unroll
  for (int kt = 0; kt < 16; ++kt) {
    int nt = 0 * 4 + wid;
    b1f[kt] = *(const short8*)(w1sw + ((size_t)((s * 32 + nt) * 16 + kt)) * 512 + lane * 8);
  }

  __syncthreads();   // Xs ready

  for (int c = 0; c < 8; ++c) {
    // acc1 init = b1 bias for this wave's hid tile (c*128 + wid*32).
    f32x16 acc1[2];
    #pragma unroll
    for (int g = 0; g < 4; ++g) {
      float4e bv = *(const float4e*)(b1 + s * D_HID + c * 128 + wid * 32 + g * 8 + hk * 4);
      #pragma unroll
      for (int q = 0; q < 4; ++q) {
        acc1[0][g * 4 + q] = bv[q];
        acc1[1][g * 4 + q] = bv[q];
      }
    }
    // ---- GEMM1: H^T tile [32 hid x 64 rows] = W1^T @ X^T, K=256 ----
    __builtin_amdgcn_s_setprio(1);
    #pragma unroll
    for (int kt = 0; kt < 16; ++kt) {
      short8 xb[2];
      #pragma unroll
      for (int bt = 0; bt < 2; ++bt)
        xb[bt] = *(const short8*)(Xs + (bt * 32 + lr) * XS_STRIDE + kt * 16 + lk);
      #pragma unroll
      for (int bt = 0; bt < 2; ++bt)
        acc1[bt] = __builtin_amdgcn_mfma_f32_32x32x16_bf16(b1f[kt], xb[bt], acc1[bt], 0, 0, 0);
    }
    __builtin_amdgcn_s_setprio(0);
    // ---- prefetch GEMM2 W2-fragments (latency hidden under silu+barrier) ----
    short8 b2f[16];
    #pragma unroll
    for (int kt = 0; kt < 8; ++kt)
      #pragma unroll
      for (int ot = 0; ot < 2; ++ot) {
        int nt = wid * 2 + ot;
        b2f[kt * 2 + ot] = *(const short8*)(w2sw + ((size_t)((s * 8 + nt) * 64 + c * 8 + kt)) * 512 + lane * 8);
      }
    // ---- silu -> Hs[c&1] (cvt_pk packed, 8B writes: 4 consecutive hid/lane) ----
    short* hsb = Hs[c & 1];
    #pragma unroll
    for (int bt = 0; bt < 2; ++bt) {
      #pragma unroll
      for (int g = 0; g < 4; ++g) {
        float p0 = acc1[bt][g * 4 + 0], p1 = acc1[bt][g * 4 + 1];
        float p2 = acc1[bt][g * 4 + 2], p3 = acc1[bt][g * 4 + 3];
        float sv0 = p0 * __builtin_amdgcn_rcpf(1.0f + __expf(-p0));
        float sv1 = p1 * __builtin_amdgcn_rcpf(1.0f + __expf(-p1));
        float sv2 = p2 * __builtin_amdgcn_rcpf(1.0f + __expf(-p2));
        float sv3 = p3 * __builtin_amdgcn_rcpf(1.0f + __expf(-p3));
        uint2e h;
        h.x = cvt_pk_bf16(sv0, sv1);
        h.y = cvt_pk_bf16(sv2, sv3);
        *(uint2e*)(hsb + (bt * 32 + lr) * HS_STRIDE + wid * 32 + g * 8 + hk * 4) = h;
      }
    }
    __syncthreads();   // Hs[c&1] visible; prior readers of Hs[(c+1)&1] done
    // ---- prefetch next chunk's W1-fragments (hidden under GEMM2 MFMA) ----
    if (c < 7) {
      #pragma unroll
      for (int kt = 0; kt < 16; ++kt) {
        int nt = (c + 1) * 4 + wid;
        b1f[kt] = *(const short8*)(w1sw + ((size_t)((s * 32 + nt) * 16 + kt)) * 512 + lane * 8);
      }
    }
    // ---- GEMM2 partial: Y^T += W2^T @ H^T (K-slice c: 8 ksteps of 16) ----
    __builtin_amdgcn_s_setprio(1);
    #pragma unroll
    for (int kt = 0; kt < 8; ++kt) {
      short8 hb[2];
      #pragma unroll
      for (int bt = 0; bt < 2; ++bt)
        hb[bt] = *(const short8*)(hsb + (bt * 32 + lr) * HS_STRIDE + kt * 16 + lk);
      #pragma unroll
      for (int ot = 0; ot < 2; ++ot)
        #pragma unroll
        for (int bt = 0; bt < 2; ++bt)
          accY[ot][bt] = __builtin_amdgcn_mfma_f32_32x32x16_bf16(b2f[kt * 2 + ot], hb[bt], accY[ot][bt], 0, 0, 0);
    }
    __builtin_amdgcn_s_setprio(0);
  }

  // ---- epilogue: scatter Y rows, 16B per lane (bias already folded in) ----
  #pragma unroll
  for (int ot = 0; ot < 2; ++ot) {
    #pragma unroll
    for (int bt = 0; bt < 2; ++bt) {
      if (rowIdx[bt] >= 0) {
        #pragma unroll
        for (int g = 0; g < 4; ++g) {
          float4e o;
          o[0] = accY[ot][bt][g * 4 + 0];
          o[1] = accY[ot][bt][g * 4 + 1];
          o[2] = accY[ot][bt][g * 4 + 2];
          o[3] = accY[ot][bt][g * 4 + 3];
          *(float4e*)(out + (size_t)rowIdx[bt] * D_OUT + wid * 64 + ot * 32 + g * 8 + hk * 4) = o;
        }
      }
    }
  }
}

extern "C" void kernel_launch(void* const* d_in, const int* in_sizes, int n_in,
                              void* d_out, int out_size, void* d_ws, size_t ws_size,
                              hipStream_t stream) {
  const float* x  = (const float*)d_in[0];
  const int* spc  = (const int*)d_in[1];
  const float* W1 = (const float*)d_in[2];
  const float* b1 = (const float*)d_in[3];
  const float* W2 = (const float*)d_in[4];
  const float* b2 = (const float*)d_in[5];
  float* out = (float*)d_out;

  int*   cnt    = (int*)d_ws;
  int*   bucket = (int*)((char*)d_ws + WS_BUCKET_OFF);
  short* w1sw   = (short*)((char*)d_ws + WS_W1_OFF);
  short* w2sw   = (short*)((char*)d_ws + WS_W2_OFF);

  prep_kernel<<<1024, 256, 0, stream>>>(W1, W2, w1sw, w2sw, cnt);
  count_fill_kernel<<<CF_BLOCKS, 256, 0, stream>>>(spc, cnt, bucket);
  fused_kernel<<<4 * TPS, 256, 0, stream>>>(x, cnt, bucket, w1sw, w2sw, b1, b2, out);
}

// Round 11
// 224.949 us; speedup vs baseline: 1.7534x; 1.0345x over previous
//
#include <hip/hip_runtime.h>
#include <hip/hip_bf16.h>

// CentralSpecificModel: per-species 2-layer MLP (256 -> 1024 -> 256), 4 species,
// N=65536 rows, fp32 in/out. Bucket rows by species; fused per-64-row-tile
// kernel does GEMM1+silu+GEMM2, swapped operands (weights as A, X/H as B ->
// H^T/Y^T), 32x32x16 bf16 MFMA (R12-verified layout; bank conflicts 7x lower
// than 16x16), batched frag prefetch.
// R13: target OCCUPANCY 2->3 blocks/CU via LDS 74752->53248 (Xs 64x264 +
// SINGLE-buffered Hs 64x152; 3x53248=159744 <= 160K). Single-buffer needs the
// two-barrier deferred-write scheme (R5/R7-proven correct): silu->regs,
// barrier (drain prior GEMM2 readers), write Hs, barrier (publish), GEMM2.
// launch_bounds stays (256,2) — R5's disaster was its (256,3) cap + 16x16's
// ~200-reg footprint; R12's 32x32 kernel allocates 124 VGPR freely. Extra
// barrier wait is covered by the 3rd independent block per CU (independent
// blocks de-phase naturally — the only overlap mechanism left after R10/R11
// protocol failures). count_fill reverted to 32 blocks (R12's 8-block variant
// grew the gap 96->106). If Occupancy stays ~17% => registers bind, not LDS.

#define N_ATOMS 65536
#define D_IN 256
#define D_HID 1024
#define D_OUT 256
#define TPS 1024   // max 64-row tiles per species (worst case: all rows one species)

typedef __attribute__((ext_vector_type(8))) short short8;
typedef __attribute__((ext_vector_type(4))) float float4e;
typedef __attribute__((ext_vector_type(16))) float f32x16;
typedef __attribute__((ext_vector_type(2))) unsigned uint2e;
typedef __attribute__((ext_vector_type(4))) unsigned uint4e;

// ws layout (bytes):
//   [0, 256)           cnt[4] padded: cnt[s] at int offset s*16 (64B apart)
//   [256, 1048832)     bucket[4][65536] int
//   [1048832, 3145984) W1 swizzled bf16 fragments (4*256*1024)
//   [3145984, 5243136) W2 swizzled bf16 fragments (4*1024*256)
#define WS_BUCKET_OFF 256
#define WS_W1_OFF 1048832
#define WS_W2_OFF 3145984

__device__ __forceinline__ short f2bf(float f) {
  unsigned u = __builtin_bit_cast(unsigned, f);
  unsigned r = (u + 0x7FFFu + ((u >> 16) & 1u)) >> 16;   // round-to-nearest-even
  return (short)r;
}

// Two f32 -> packed 2x bf16 in one instruction (low half = a, high half = b).
__device__ __forceinline__ unsigned cvt_pk_bf16(float a, float b) {
  unsigned r;
  asm("v_cvt_pk_bf16_f32 %0, %1, %2" : "=v"(r) : "v"(a), "v"(b));
  return r;
}

// Swizzle W1/W2 fp32 -> bf16 MFMA 32x32x16 A-fragment order (swapped form:
// weights are the A operand, A = W^T). Lane l of frag (nt,kt) holds
// W[kt*16 + 8*(l>>5) + j][nt*32 + (l&31)], j=0..7 (16B contiguous per lane).
// W1: 4 species x 32 nt x 16 kt frags; W2: 4 x 8 nt x 64 kt frags.
__global__ void prep_kernel(const float* __restrict__ W1, const float* __restrict__ W2,
                            short* __restrict__ w1sw, short* __restrict__ w2sw,
                            int* __restrict__ cnt) {
  int gid = blockIdx.x * 256 + threadIdx.x;   // 262144 threads
  if (gid < 64) cnt[gid] = 0;
  int lane = gid & 63;
  int lc = lane & 31;            // output-dim col within 32-tile
  int lk = (lane >> 5) * 8;      // k base within 16-kstep
  if (gid < 131072) {            // W1: [4][256][1024], NT=32, KT=16
    int kt = (gid >> 6) & 15;
    int nt = (gid >> 10) & 31;
    int s  = gid >> 15;
    const float* src = W1 + ((size_t)(s * 256 + kt * 16 + lk)) * 1024 + nt * 32 + lc;
    short8 v;
    for (int j = 0; j < 8; ++j) v[j] = f2bf(src[(size_t)j * 1024]);
    *(short8*)(w1sw + (size_t)gid * 8) = v;
  } else {                       // W2: [4][1024][256], NT=8, KT=64
    int g = gid - 131072;
    int kt = (g >> 6) & 63;
    int nt = (g >> 12) & 7;
    int s  = g >> 15;
    const float* src = W2 + ((size_t)(s * 1024 + kt * 16 + lk)) * 256 + nt * 32 + lc;
    short8 v;
    for (int j = 0; j < 8; ++j) v[j] = f2bf(src[(size_t)j * 256]);
    *(short8*)(w2sw + (size_t)g * 8) = v;
  }
}

// Bucket rows by species. 32 blocks x 2048 rows (R8-verified config).
// Two-pass block-internal histogram; ONE atomicAdd per species per block.
#define CF_BLOCKS 32
#define CF_ITERS 8
__global__ void count_fill_kernel(const int* __restrict__ species,
                                  int* __restrict__ cnt, int* __restrict__ bucket) {
  int tid = threadIdx.x;
  int lane = tid & 63, wid = tid >> 6;
  __shared__ int wcnt[CF_ITERS][4][4];   // [iter][wave][species]
  __shared__ int wb[CF_ITERS][4][4];     // exclusive prefix within block
  __shared__ int base_sm[4];
  int sv[CF_ITERS], rk[CF_ITERS];
  unsigned long long below = (1ull << lane) - 1ull;
  int base_i = blockIdx.x * (CF_ITERS * 256);
  #pragma unroll
  for (int it = 0; it < CF_ITERS; ++it) {
    int s = species[base_i + it * 256 + tid] & 3;
    sv[it] = s;
    unsigned long long m0 = __ballot(s == 0);
    unsigned long long m1 = __ballot(s == 1);
    unsigned long long m2 = __ballot(s == 2);
    unsigned long long m3 = __ballot(s == 3);
    unsigned long long ms = (s == 0) ? m0 : (s == 1) ? m1 : (s == 2) ? m2 : m3;
    rk[it] = __popcll(ms & below);
    if (lane == 0) {
      wcnt[it][wid][0] = __popcll(m0);
      wcnt[it][wid][1] = __popcll(m1);
      wcnt[it][wid][2] = __popcll(m2);
      wcnt[it][wid][3] = __popcll(m3);
    }
  }
  __syncthreads();
  if (tid < 4) {
    int ss = tid, run = 0;
    for (int it = 0; it < CF_ITERS; ++it)
      for (int w = 0; w < 4; ++w) {
        wb[it][w][ss] = run;
        run += wcnt[it][w][ss];
      }
    base_sm[ss] = atomicAdd(&cnt[ss * 16], run);
  }
  __syncthreads();
  #pragma unroll
  for (int it = 0; it < CF_ITERS; ++it) {
    int ss = sv[it];
    bucket[ss * N_ATOMS + base_sm[ss] + wb[it][wid][ss] + rk[it]] = base_i + it * 256 + tid;
  }
}

// Fused per-tile MLP, swapped-operand 32x32x16 form. Block = 256 threads
// (4 waves), tile = 64 rows (2 row-tiles of 32). Per chunk c (8 x 128 hid):
// GEMM1: wave owns hid-tile nt=c*4+wid (32 hid x 64 rows), 16 ksteps x 2 bt;
// silu->regs; barrier (prior GEMM2 readers done); write Hs; barrier; GEMM2:
// wave owns out cols [wid*64,+64), 8 ksteps x 2 ot x 2 bt.
// C/D: col(=x-row)=lane&31, row=(reg&3)+8*(reg>>2)+4*(lane>>5).
// LDS: Xs 64x264 (33792) + Hs 64x152 (19456) = 53248B -> 3 blocks/CU.
#define XS_STRIDE 264
#define HS_STRIDE 152
__global__ __launch_bounds__(256, 2) void fused_kernel(
    const float* __restrict__ x, const int* __restrict__ cntArr,
    const int* __restrict__ bucket, const short* __restrict__ w1sw,
    const short* __restrict__ w2sw, const float* __restrict__ b1,
    const float* __restrict__ b2, float* __restrict__ out) {
  int bid = blockIdx.x;
  // XCD swizzle: bid%8 round-robins XCDs; give species s to XCD pair {2s,2s+1}
  // so each XCD L2 only holds ~1MB of weight fragments.
  int s = (bid & 7) >> 1;
  int t = ((bid >> 3) << 1) | (bid & 1);
  int cnt = cntArr[s * 16];
  int r0 = t * 64;
  if (r0 >= cnt) return;
  int nrows = min(64, cnt - r0);
  const int* buck = bucket + s * N_ATOMS + r0;

  __shared__ short Xs[64 * XS_STRIDE];   // 33792 B
  __shared__ short Hs[64 * HS_STRIDE];   // 19456 B (single-buffered)

  int tid = threadIdx.x;

  // Stage gathered x tile -> bf16 LDS (cvt_pk packed). 2048 8-elem groups.
  for (int i = 0; i < 8; ++i) {
    int id = tid + i * 256;
    int r = id >> 5;          // row 0..63
    int g = id & 31;          // 8-float group
    float4 f0 = {}, f1 = {};
    if (r < nrows) {
      const float4* src = (const float4*)(x + (size_t)buck[r] * D_IN + g * 8);
      f0 = src[0];
      f1 = src[1];
    }
    uint4e v;
    v.x = cvt_pk_bf16(f0.x, f0.y);
    v.y = cvt_pk_bf16(f0.z, f0.w);
    v.z = cvt_pk_bf16(f1.x, f1.y);
    v.w = cvt_pk_bf16(f1.z, f1.w);
    *(uint4e*)(Xs + r * XS_STRIDE + g * 8) = v;
  }

  int lane = tid & 63;
  int wid = tid >> 6;
  int lr = lane & 31;          // x-row within 32-tile (C/D col)
  int hk = lane >> 5;          // K-half select (0/1); also C/D row +4 offset
  int lk = hk * 8;             // k base within 16-kstep

  // Row gather indices for the epilogue (per 32-row tile).
  int rowIdx[2];
  #pragma unroll
  for (int bt = 0; bt < 2; ++bt) {
    int r = bt * 32 + lr;
    rowIdx[bt] = (r < nrows) ? buck[r] : -1;
  }

  // accY init = b2 bias (folded). Wave covers out cols [wid*64, wid*64+64).
  // acc element 4g+q <-> out offset g*8 + hk*4 + q.
  f32x16 accY[2][2];
  #pragma unroll
  for (int ot = 0; ot < 2; ++ot) {
    #pragma unroll
    for (int g = 0; g < 4; ++g) {
      float4e bv = *(const float4e*)(b2 + s * D_OUT + wid * 64 + ot * 32 + g * 8 + hk * 4);
      #pragma unroll
      for (int q = 0; q < 4; ++q) {
        accY[ot][0][g * 4 + q] = bv[q];
        accY[ot][1][g * 4 + q] = bv[q];
      }
    }
  }

  // Preload GEMM1 W1-fragments for c=0 (16 batched loads, one latency exposure).
  short8 b1f[16];
  #pragma unroll
  for (int kt = 0; kt < 16; ++kt) {
    int nt = 0 * 4 + wid;
    b1f[kt] = *(const short8*)(w1sw + ((size_t)((s * 32 + nt) * 16 + kt)) * 512 + lane * 8);
  }

  __syncthreads();   // Xs ready

  for (int c = 0; c < 8; ++c) {
    // acc1 init = b1 bias for this wave's hid tile (c*128 + wid*32).
    f32x16 acc1[2];
    #pragma unroll
    for (int g = 0; g < 4; ++g) {
      float4e bv = *(const float4e*)(b1 + s * D_HID + c * 128 + wid * 32 + g * 8 + hk * 4);
      #pragma unroll
      for (int q = 0; q < 4; ++q) {
        acc1[0][g * 4 + q] = bv[q];
        acc1[1][g * 4 + q] = bv[q];
      }
    }
    // ---- GEMM1: H^T tile [32 hid x 64 rows] = W1^T @ X^T, K=256 ----
    __builtin_amdgcn_s_setprio(1);
    #pragma unroll
    for (int kt = 0; kt < 16; ++kt) {
      short8 xb[2];
      #pragma unroll
      for (int bt = 0; bt < 2; ++bt)
        xb[bt] = *(const short8*)(Xs + (bt * 32 + lr) * XS_STRIDE + kt * 16 + lk);
      #pragma unroll
      for (int bt = 0; bt < 2; ++bt)
        acc1[bt] = __builtin_amdgcn_mfma_f32_32x32x16_bf16(b1f[kt], xb[bt], acc1[bt], 0, 0, 0);
    }
    __builtin_amdgcn_s_setprio(0);
    // ---- prefetch GEMM2 W2-fragments (latency hidden under silu) ----
    short8 b2f[16];
    #pragma unroll
    for (int kt = 0; kt < 8; ++kt)
      #pragma unroll
      for (int ot = 0; ot < 2; ++ot) {
        int nt = wid * 2 + ot;
        b2f[kt * 2 + ot] = *(const short8*)(w2sw + ((size_t)((s * 8 + nt) * 64 + c * 8 + kt)) * 512 + lane * 8);
      }
    // ---- silu -> REGISTERS (Hs write deferred past the drain barrier) ----
    uint2e hreg[2][4];
    #pragma unroll
    for (int bt = 0; bt < 2; ++bt) {
      #pragma unroll
      for (int g = 0; g < 4; ++g) {
        float p0 = acc1[bt][g * 4 + 0], p1 = acc1[bt][g * 4 + 1];
        float p2 = acc1[bt][g * 4 + 2], p3 = acc1[bt][g * 4 + 3];
        float sv0 = p0 * __builtin_amdgcn_rcpf(1.0f + __expf(-p0));
        float sv1 = p1 * __builtin_amdgcn_rcpf(1.0f + __expf(-p1));
        float sv2 = p2 * __builtin_amdgcn_rcpf(1.0f + __expf(-p2));
        float sv3 = p3 * __builtin_amdgcn_rcpf(1.0f + __expf(-p3));
        hreg[bt][g].x = cvt_pk_bf16(sv0, sv1);
        hreg[bt][g].y = cvt_pk_bf16(sv2, sv3);
      }
    }
    __syncthreads();   // prior chunk's GEMM2 readers of Hs are done
    // ---- Hs writes (8B packed: 4 consecutive hid per lane) ----
    #pragma unroll
    for (int bt = 0; bt < 2; ++bt)
      #pragma unroll
      for (int g = 0; g < 4; ++g)
        *(uint2e*)(Hs + (bt * 32 + lr) * HS_STRIDE + wid * 32 + g * 8 + hk * 4) = hreg[bt][g];
    __syncthreads();   // Hs chunk c visible to all waves
    // ---- prefetch next chunk's W1-fragments (hidden under GEMM2 MFMA) ----
    if (c < 7) {
      #pragma unroll
      for (int kt = 0; kt < 16; ++kt) {
        int nt = (c + 1) * 4 + wid;
        b1f[kt] = *(const short8*)(w1sw + ((size_t)((s * 32 + nt) * 16 + kt)) * 512 + lane * 8);
      }
    }
    // ---- GEMM2 partial: Y^T += W2^T @ H^T (K-slice c: 8 ksteps of 16) ----
    __builtin_amdgcn_s_setprio(1);
    #pragma unroll
    for (int kt = 0; kt < 8; ++kt) {
      short8 hb[2];
      #pragma unroll
      for (int bt = 0; bt < 2; ++bt)
        hb[bt] = *(const short8*)(Hs + (bt * 32 + lr) * HS_STRIDE + kt * 16 + lk);
      #pragma unroll
      for (int ot = 0; ot < 2; ++ot)
        #pragma unroll
        for (int bt = 0; bt < 2; ++bt)
          accY[ot][bt] = __builtin_amdgcn_mfma_f32_32x32x16_bf16(b2f[kt * 2 + ot], hb[bt], accY[ot][bt], 0, 0, 0);
    }
    __builtin_amdgcn_s_setprio(0);
  }

  // ---- epilogue: scatter Y rows, 16B per lane (bias already folded in) ----
  #pragma unroll
  for (int ot = 0; ot < 2; ++ot) {
    #pragma unroll
    for (int bt = 0; bt < 2; ++bt) {
      if (rowIdx[bt] >= 0) {
        #pragma unroll
        for (int g = 0; g < 4; ++g) {
          float4e o;
          o[0] = accY[ot][bt][g * 4 + 0];
          o[1] = accY[ot][bt][g * 4 + 1];
          o[2] = accY[ot][bt][g * 4 + 2];
          o[3] = accY[ot][bt][g * 4 + 3];
          *(float4e*)(out + (size_t)rowIdx[bt] * D_OUT + wid * 64 + ot * 32 + g * 8 + hk * 4) = o;
        }
      }
    }
  }
}

extern "C" void kernel_launch(void* const* d_in, const int* in_sizes, int n_in,
                              void* d_out, int out_size, void* d_ws, size_t ws_size,
                              hipStream_t stream) {
  const float* x  = (const float*)d_in[0];
  const int* spc  = (const int*)d_in[1];
  const float* W1 = (const float*)d_in[2];
  const float* b1 = (const float*)d_in[3];
  const float* W2 = (const float*)d_in[4];
  const float* b2 = (const float*)d_in[5];
  float* out = (float*)d_out;

  int*   cnt    = (int*)d_ws;
  int*   bucket = (int*)((char*)d_ws + WS_BUCKET_OFF);
  short* w1sw   = (short*)((char*)d_ws + WS_W1_OFF);
  short* w2sw   = (short*)((char*)d_ws + WS_W2_OFF);

  prep_kernel<<<1024, 256, 0, stream>>>(W1, W2, w1sw, w2sw, cnt);
  count_fill_kernel<<<CF_BLOCKS, 256, 0, stream>>>(spc, cnt, bucket);
  fused_kernel<<<4 * TPS, 256, 0, stream>>>(x, cnt, bucket, w1sw, w2sw, b1, b2, out);
}